// Round 1
// baseline (273.796 us; speedup 1.0000x reference)
//
#include <hip/hip_runtime.h>
#include <hip/hip_bf16.h>
#include <stdint.h>

// Problem dims (fixed): B=4, S=2048, IN=1024, OUT=4096 -> M=8192, K=1024, N=4096
#define M_DIM 8192
#define K_DIM 1024
#define N_DIM 4096

typedef __bf16 bf16x8 __attribute__((ext_vector_type(8)));
typedef float  f32x4  __attribute__((ext_vector_type(4)));

__device__ __forceinline__ uint16_t f2bf(float f) {
  union { float f; uint32_t u; } x; x.f = f;
  uint32_t u = x.u;
  return (uint16_t)((u + 0x7FFFu + ((u >> 16) & 1u)) >> 16);  // RNE
}

// ---------------- kernel 1: input fp32 -> bf16 ----------------
__global__ __launch_bounds__(256) void convert_bf16_kernel(
    const float* __restrict__ in, uint16_t* __restrict__ out, int n4) {
  int i = blockIdx.x * 256 + threadIdx.x;
  if (i >= n4) return;
  float4 v = ((const float4*)in)[i];
  ushort4 o;
  o.x = f2bf(v.x); o.y = f2bf(v.y); o.z = f2bf(v.z); o.w = f2bf(v.w);
  ((ushort4*)out)[i] = o;
}

// ---------------- kernel 2: fold everything into W5^T (N x K) bf16 ----------------
// One thread per (in-pair m_in, out-pair m_out): computes a 2x2 block of W5.
// Chain (verified against reference einsums):
//  m2[r,2mi]   =  ci*w[r,ia0] + si*w[r,ia1];  m2[r,2mi+1] = -si*w[r,ia0] + ci*w[r,ia1]
//  m3[i,2mo]   =  co*m2[r0,i] - so*m2[r1,i];  m3[i,2mo+1] =  so*m2[r0,i] + co*m2[r1,i]
//  m3[i,n]    *=  mask[n,i]
//  m4[i,2mo]   =  co*m3[i,2mo] + so*m3[i,2mo+1];  m4[i,2mo+1] = -so*m3[i,2mo] + co*m3[i,2mo+1]
//  m5[:,out_mapping[n]] = m4[:,n]   (o0=r0, o1=r1)
//  W5[ia0,o]   =  ci*m5[2mi,o] - si*m5[2mi+1,o];  W5[ia1,o] = si*m5[2mi,o] + ci*m5[2mi+1,o]
__global__ __launch_bounds__(256) void build_w_kernel(
    const float* __restrict__ weight,      // (4096, 1024)
    const float* __restrict__ mask,        // (4096, 1024)
    const float* __restrict__ in_scores,   // (512)
    const float* __restrict__ out_scores,  // (2048)
    const int*   __restrict__ in_mapping,  // (1024)
    const int*   __restrict__ out_mapping, // (4096)
    uint16_t*    __restrict__ w5t)         // (4096, 1024) bf16: row=o, col=i
{
  int tid  = blockIdx.x * 256 + threadIdx.x;     // [0, 512*2048)
  int m_in  = tid & 511;
  int m_out = tid >> 9;

  float ai = in_scores[m_in];
  float ao = out_scores[m_out];
  float si = sinf(ai), ci = cosf(ai);
  float so = sinf(ao), co = cosf(ao);

  int ia0 = in_mapping[2 * m_in];
  int ia1 = in_mapping[2 * m_in + 1];
  int r0  = out_mapping[2 * m_out];
  int r1  = out_mapping[2 * m_out + 1];

  float w00 = weight[(size_t)r0 * K_DIM + ia0];
  float w01 = weight[(size_t)r0 * K_DIM + ia1];
  float w10 = weight[(size_t)r1 * K_DIM + ia0];
  float w11 = weight[(size_t)r1 * K_DIM + ia1];

  // m2 (in-side inverse rotation of weight columns)
  float a00 =  ci * w00 + si * w01;   // m2[r0, 2mi]
  float a01 = -si * w00 + ci * w01;   // m2[r0, 2mi+1]
  float a10 =  ci * w10 + si * w11;   // m2[r1, 2mi]
  float a11 = -si * w10 + ci * w11;   // m2[r1, 2mi+1]

  // m3 (out-side inverse rotation, transposed form)
  float b00 = co * a00 - so * a10;    // m3[2mi,   2mo]
  float b10 = co * a01 - so * a11;    // m3[2mi+1, 2mo]
  float b01 = so * a00 + co * a10;    // m3[2mi,   2mo+1]
  float b11 = so * a01 + co * a11;    // m3[2mi+1, 2mo+1]

  // mask (in m3 coordinates)
  const float2 mk0 = *(const float2*)&mask[(size_t)(2 * m_out) * K_DIM + 2 * m_in];
  const float2 mk1 = *(const float2*)&mask[(size_t)(2 * m_out + 1) * K_DIM + 2 * m_in];
  b00 *= mk0.x; b10 *= mk0.y;
  b01 *= mk1.x; b11 *= mk1.y;

  // m4 (final out-pair rotation folded into columns)
  float c00 =  co * b00 + so * b01;   // m4[2mi,   2mo]
  float c10 =  co * b10 + so * b11;   // m4[2mi+1, 2mo]
  float c01 = -so * b00 + co * b01;   // m4[2mi,   2mo+1]
  float c11 = -so * b10 + co * b11;   // m4[2mi+1, 2mo+1]

  // input-side fold (rows scattered by in_mapping)
  float d00 = ci * c00 - si * c10;    // W5[ia0, o0]
  float d10 = si * c00 + ci * c10;    // W5[ia1, o0]
  float d01 = ci * c01 - si * c11;    // W5[ia0, o1]
  float d11 = si * c01 + ci * c11;    // W5[ia1, o1]

  // column scatter: o0 = out_mapping[2mo] = r0, o1 = r1. Store W5^T[o, i].
  w5t[(size_t)r0 * K_DIM + ia0] = f2bf(d00);
  w5t[(size_t)r0 * K_DIM + ia1] = f2bf(d10);
  w5t[(size_t)r1 * K_DIM + ia0] = f2bf(d01);
  w5t[(size_t)r1 * K_DIM + ia1] = f2bf(d11);
}

// ---------------- kernel 3: GEMM out = A(8192x1024) * W5(1024x4096), bf16 MFMA ----------------
// m97-ladder structure: 128x128 tile, BK=32, 4 waves, 4x4 16x16x32 MFMAs per wave,
// global_load_lds width=16 staging, contiguous LDS (wave reads contiguous 1KB -> conflict-free).

__device__ __forceinline__ void async_load16(const uint16_t* g, uint16_t* lds_wave_uniform) {
  __builtin_amdgcn_global_load_lds(
      (const __attribute__((address_space(1))) uint32_t*)g,
      (__attribute__((address_space(3))) uint32_t*)lds_wave_uniform,
      16, 0, 0);
}

__global__ __launch_bounds__(256, 2) void gemm_kernel(
    const uint16_t* __restrict__ A,   // (8192, 1024) bf16
    const uint16_t* __restrict__ BT,  // (4096, 1024) bf16 (W5^T, row=n, col=k)
    float* __restrict__ C)            // (8192, 4096) fp32
{
  __shared__ __align__(16) uint16_t As[128 * 32];
  __shared__ __align__(16) uint16_t Bs[128 * 32];

  const int tid  = threadIdx.x;
  const int wave = tid >> 6;
  const int lane = tid & 63;
  const int quad = lane >> 4;
  const int rr   = lane & 15;
  const int bn   = blockIdx.x;      // N tile [0,32)
  const int bm   = blockIdx.y;      // M tile [0,64)
  const int wm   = (wave >> 1) * 64;
  const int wn   = (wave & 1) * 64;

  f32x4 acc[4][4] = {};

  // staging: 512 chunks of 16B per matrix; thread t covers chunks t and t+256.
  // chunk c -> tile row c>>2, k-subblock (c&3)*8 elements; LDS offset c*16 B.
  const int row0 = tid >> 2;               // 0..63
  const int kb   = (lane & 3) * 8;         // element offset in row
  const uint16_t* gA0 = A  + (size_t)(bm * 128 + row0) * K_DIM + kb;
  const uint16_t* gA1 = A  + (size_t)(bm * 128 + row0 + 64) * K_DIM + kb;
  const uint16_t* gB0 = BT + (size_t)(bn * 128 + row0) * K_DIM + kb;
  const uint16_t* gB1 = BT + (size_t)(bn * 128 + row0 + 64) * K_DIM + kb;
  uint16_t* lA0 = &As[wave * 512];          // wave-uniform; HW adds lane*16B
  uint16_t* lA1 = &As[2048 + wave * 512];
  uint16_t* lB0 = &Bs[wave * 512];
  uint16_t* lB1 = &Bs[2048 + wave * 512];

  for (int k0 = 0; k0 < K_DIM; k0 += 32) {
    async_load16(gA0 + k0, lA0);
    async_load16(gA1 + k0, lA1);
    async_load16(gB0 + k0, lB0);
    async_load16(gB1 + k0, lB1);
    __syncthreads();   // compiler drains vmcnt before s_barrier

    bf16x8 af[4], bfr[4];
#pragma unroll
    for (int i = 0; i < 4; i++)
      af[i] = *reinterpret_cast<const bf16x8*>(&As[(wm + i * 16 + rr) * 32 + quad * 8]);
#pragma unroll
    for (int j = 0; j < 4; j++)
      bfr[j] = *reinterpret_cast<const bf16x8*>(&Bs[(wn + j * 16 + rr) * 32 + quad * 8]);

#pragma unroll
    for (int i = 0; i < 4; i++)
#pragma unroll
      for (int j = 0; j < 4; j++)
        acc[i][j] = __builtin_amdgcn_mfma_f32_16x16x32_bf16(af[i], bfr[j], acc[i][j], 0, 0, 0);

    __syncthreads();
  }

  // epilogue: D layout col = lane&15 (n), row = quad*4 + reg (m)
#pragma unroll
  for (int i = 0; i < 4; i++) {
#pragma unroll
    for (int j = 0; j < 4; j++) {
      const int colg = bn * 128 + wn + j * 16 + rr;
#pragma unroll
      for (int rg = 0; rg < 4; rg++) {
        const int rowg = bm * 128 + wm + i * 16 + quad * 4 + rg;
        C[(size_t)rowg * N_DIM + colg] = acc[i][j][rg];
      }
    }
  }
}

extern "C" void kernel_launch(void* const* d_in, const int* in_sizes, int n_in,
                              void* d_out, int out_size, void* d_ws, size_t ws_size,
                              hipStream_t stream) {
  const float* input      = (const float*)d_in[0];
  const float* weight     = (const float*)d_in[1];
  const float* mask       = (const float*)d_in[2];
  const float* in_scores  = (const float*)d_in[3];
  const float* out_scores = (const float*)d_in[4];
  const int*   in_mapping = (const int*)d_in[5];
  const int*   out_mapping= (const int*)d_in[6];
  // d_in[7] = out_mapping_reverse (folded away), d_in[8] = temperature (unused)
  float* out = (float*)d_out;

  uint16_t* a_bf16 = (uint16_t*)d_ws;                              // 8192*1024 bf16 = 16 MB
  uint16_t* w5t    = (uint16_t*)d_ws + (size_t)M_DIM * K_DIM;      // 4096*1024 bf16 = 8 MB

  convert_bf16_kernel<<<(M_DIM * K_DIM / 4 + 255) / 256, 256, 0, stream>>>(
      input, a_bf16, M_DIM * K_DIM / 4);

  build_w_kernel<<<(512 * 2048) / 256, 256, 0, stream>>>(
      weight, mask, in_scores, out_scores, in_mapping, out_mapping, w5t);

  dim3 grid(N_DIM / 128, M_DIM / 128);  // (32, 64)
  gemm_kernel<<<grid, 256, 0, stream>>>(a_bf16, w5t, out);
}